// Round 7
// baseline (299.928 us; speedup 1.0000x reference)
//
#include <hip/hip_runtime.h>

typedef unsigned short u16;
typedef unsigned int u32;
typedef u16 u16x8 __attribute__((ext_vector_type(8)));
typedef u16 u16x4 __attribute__((ext_vector_type(4)));
typedef __bf16 bf16x8 __attribute__((ext_vector_type(8)));
typedef float f32x4 __attribute__((ext_vector_type(4)));

// ---------- helpers ----------
__device__ __forceinline__ u16 f2bf(float f) {
    u32 u = __builtin_bit_cast(u32, f);
    u32 r = (u + 0x7fffu + ((u >> 16) & 1u)) >> 16;
    return (u16)r;
}
__device__ __forceinline__ void async16(const u16* g, u16* lds_base) {
    // HW writes lds_base + lane*16B; lds_base must be wave-uniform.
    __builtin_amdgcn_global_load_lds(
        (const __attribute__((address_space(1))) void*)g,
        (__attribute__((address_space(3))) void*)lds_base, 16, 0, 0);
}
__device__ __forceinline__ void storeC(float* p, float v) { *p = v; }
__device__ __forceinline__ void storeC(u16* p, float v)   { *p = f2bf(v); }

// ---------- fp32 -> bf16 convert (8 elems/thread) ----------
__global__ void cvt_f32_bf16(const float* __restrict__ in, u16* __restrict__ out, long n) {
    long idx = ((long)blockIdx.x * blockDim.x + threadIdx.x) * 8;
    if (idx >= n) return;
    float4 a = *(const float4*)(in + idx);
    float4 b = *(const float4*)(in + idx + 4);
    u16x8 o;
    o[0] = f2bf(a.x); o[1] = f2bf(a.y); o[2] = f2bf(a.z); o[3] = f2bf(a.w);
    o[4] = f2bf(b.x); o[5] = f2bf(b.y); o[6] = f2bf(b.z); o[7] = f2bf(b.w);
    *(u16x8*)(out + idx) = o;
}

// ---------- transpose+convert Wk/Wv -> WkvT [2048][1024] bf16 ----------
__global__ void transpose_cvt(const float* __restrict__ W0, const float* __restrict__ W1,
                              u16* __restrict__ WT) {
    __shared__ float tile[32][33];
    const float* W = (blockIdx.z == 0) ? W0 : W1;
    int n0 = blockIdx.x * 32, k0 = blockIdx.y * 32;
    int tx = threadIdx.x, ty = threadIdx.y;
#pragma unroll
    for (int r = 0; r < 4; ++r)
        tile[ty + 8 * r][tx] = W[(size_t)(k0 + ty + 8 * r) * 1024 + n0 + tx];
    __syncthreads();
#pragma unroll
    for (int r = 0; r < 4; ++r) {
        int n = n0 + ty + 8 * r;
        WT[((size_t)blockIdx.z * 1024 + n) * 1024 + k0 + tx] = f2bf(tile[tx][ty + 8 * r]);
    }
}

// ================= 256x256 pipelined bf16 MFMA GEMM (T2 swizzle, 1 barrier/phase) ====
// C[m][n] = sum_k A[m][k] * Bt[n][k].  K multiple of 128. M,N multiples of 256.
#define BAR __builtin_amdgcn_s_barrier()
#define SB0 __builtin_amdgcn_sched_barrier(0)
#define PRIO1 __builtin_amdgcn_s_setprio(1)
#define PRIO0 __builtin_amdgcn_s_setprio(0)
#define VM(n) asm volatile("s_waitcnt vmcnt(" #n ")" ::: "memory")

#define As SM[0]
#define Bs SM[1]

#define LDALO(buf) do { _Pragma("unroll") for (int mi = 0; mi < 4; ++mi) { \
    const int rA = (wm * 128 + mi * 16 + frow) * 64; \
    aLo[mi][0] = *(const bf16x8*)&As[buf][rA + xs0]; \
    aLo[mi][1] = *(const bf16x8*)&As[buf][rA + xs1]; } } while (0)

#define LDAHI(buf) do { _Pragma("unroll") for (int mi = 0; mi < 4; ++mi) { \
    const int rA = (wm * 128 + 64 + mi * 16 + frow) * 64; \
    aHi[mi][0] = *(const bf16x8*)&As[buf][rA + xs0]; \
    aHi[mi][1] = *(const bf16x8*)&As[buf][rA + xs1]; } } while (0)

#define LDBL(BL, buf) do { _Pragma("unroll") for (int ni = 0; ni < 2; ++ni) { \
    const int rB = (wn * 64 + ni * 16 + frow) * 64; \
    BL[ni][0] = *(const bf16x8*)&Bs[buf][rB + xs0]; \
    BL[ni][1] = *(const bf16x8*)&Bs[buf][rB + xs1]; } } while (0)

#define LDBHI(buf) do { _Pragma("unroll") for (int ni = 0; ni < 2; ++ni) { \
    const int rB = (wn * 64 + 32 + ni * 16 + frow) * 64; \
    bHi[ni][0] = *(const bf16x8*)&Bs[buf][rB + xs0]; \
    bHi[ni][1] = *(const bf16x8*)&Bs[buf][rB + xs1]; } } while (0)

#define MFQ00(BL) do { _Pragma("unroll") for (int mi = 0; mi < 4; ++mi) \
  _Pragma("unroll") for (int ni = 0; ni < 2; ++ni) \
  _Pragma("unroll") for (int s = 0; s < 2; ++s) \
    acc[mi][ni] = __builtin_amdgcn_mfma_f32_16x16x32_bf16(aLo[mi][s], BL[ni][s], acc[mi][ni], 0, 0, 0); } while (0)
#define MFQ01 do { _Pragma("unroll") for (int mi = 0; mi < 4; ++mi) \
  _Pragma("unroll") for (int ni = 0; ni < 2; ++ni) \
  _Pragma("unroll") for (int s = 0; s < 2; ++s) \
    acc[mi][2 + ni] = __builtin_amdgcn_mfma_f32_16x16x32_bf16(aLo[mi][s], bHi[ni][s], acc[mi][2 + ni], 0, 0, 0); } while (0)
#define MFQ11 do { _Pragma("unroll") for (int mi = 0; mi < 4; ++mi) \
  _Pragma("unroll") for (int ni = 0; ni < 2; ++ni) \
  _Pragma("unroll") for (int s = 0; s < 2; ++s) \
    acc[4 + mi][2 + ni] = __builtin_amdgcn_mfma_f32_16x16x32_bf16(aHi[mi][s], bHi[ni][s], acc[4 + mi][2 + ni], 0, 0, 0); } while (0)
#define MFQ10(BL) do { _Pragma("unroll") for (int mi = 0; mi < 4; ++mi) \
  _Pragma("unroll") for (int ni = 0; ni < 2; ++ni) \
  _Pragma("unroll") for (int s = 0; s < 2; ++s) \
    acc[4 + mi][ni] = __builtin_amdgcn_mfma_f32_16x16x32_bf16(aHi[mi][s], BL[ni][s], acc[4 + mi][ni], 0, 0, 0); } while (0)

// One K-tile, 4 phases, 1 barrier each. ds_reads issued one phase ahead;
// buf(t) restaged for t+2 at ph2/ph3/ph4 (gated by read-completion barriers);
// vmcnt(6)+BAR at ph3 guarantees buf(t+1) fully staged before ph4's lookahead reads.
#define TILEP(buf, BLC, BLN, stg, kt2, look) do { \
  LDBHI(buf); SB0; PRIO1; MFQ00(BLC); PRIO0; BAR; SB0; \
  LDAHI(buf); \
  if (stg) { stageH(buf, 0, 0, kt2); stageH(buf, 1, 0, kt2); } \
  SB0; PRIO1; MFQ01; PRIO0; BAR; SB0; \
  if (stg) stageH(buf, 1, 1, kt2); \
  SB0; PRIO1; MFQ11; PRIO0; \
  if (stg) { VM(6); } else { VM(0); } \
  BAR; SB0; \
  if (look) { LDALO((buf) ^ 1); LDBL(BLN, (buf) ^ 1); } \
  if (stg) stageH(buf, 0, 1, kt2); \
  SB0; PRIO1; MFQ10(BLC); PRIO0; BAR; SB0; \
} while (0)

// KVMODE=true: nBase 0-1023 -> Kt (transposed), 1024-2047 -> Vt (transposed).
// KVMODE=false: Bt += (mBase>>12)*btStrideB (per-batch B), normal C write.
template <typename OutT, bool KVMODE>
__global__ __launch_bounds__(512, 2) void gemm8p(
    const u16* __restrict__ A, int lda,
    const u16* __restrict__ Bt, int ldb,
    OutT* __restrict__ Cq, int ldc, int K, int nTN,
    size_t btStrideB, u16* __restrict__ Kt, u16* __restrict__ Vt) {
    __shared__ u16 SM[2][2][256 * 64];
    const int tid = threadIdx.x;
    const int wid = tid >> 6, lane = tid & 63;
    const int wm = wid >> 2, wn = wid & 3;

    const int nwg = gridDim.x;
    const int orig = blockIdx.x;
    const int id = (orig & 7) * (nwg >> 3) + (orig >> 3);
    const size_t mBase = (size_t)(id / nTN) * 256;
    const size_t nBase = (size_t)(id % nTN) * 256;

    if (!KVMODE) Bt += (mBase >> 12) * btStrideB;

    const int srow = lane >> 3;
    const int scol = (((lane & 7) ^ (srow & 7)) * 8);

    auto stageH = [&](int buf, int isB, int h, int kt) {
        const u16* g = isB ? Bt : A;
        const int ld = isB ? ldb : lda;
        const size_t rb = isB ? nBase : mBase;
        u16* lds = isB ? Bs[buf] : As[buf];
#pragma unroll
        for (int j = 0; j < 2; ++j) {
            const int rowL = isB ? ((wid >> 1) * 64 + h * 32 + (wid & 1) * 16 + j * 8)
                                 : ((wid >> 2) * 128 + h * 64 + (wid & 3) * 16 + j * 8);
            async16(g + (rb + rowL + srow) * (size_t)ld + (size_t)kt * 64 + scol,
                    lds + rowL * 64);
        }
    };

    const int frow = lane & 15;
    const int xs0 = (((lane >> 4)) ^ (frow & 7)) * 8;
    const int xs1 = ((4 + (lane >> 4)) ^ (frow & 7)) * 8;

    f32x4 acc[8][4] = {};
    bf16x8 aLo[4][2], aHi[4][2], bL0[2][2], bL1[2][2], bHi[2][2];

    // prologue: stage tiles 0 and 1 fully, then pre-read tile-0's ph1 fragments
#pragma unroll
    for (int h = 0; h < 2; ++h) { stageH(0, 0, h, 0); stageH(0, 1, h, 0); }
#pragma unroll
    for (int h = 0; h < 2; ++h) { stageH(1, 0, h, 1); stageH(1, 1, h, 1); }
    VM(8);
    BAR; SB0;
    LDALO(0); LDBL(bL0, 0);

    const int nt = K >> 6;  // even, >= 4
    for (int t = 0; t < nt; t += 2) {
        TILEP(0, bL0, bL1, (t + 2 < nt), t + 2, true);
        TILEP(1, bL1, bL0, (t + 3 < nt), t + 3, (t + 2 < nt));
    }

    const int rb4 = (lane >> 4) * 4;
    const int cx = lane & 15;
    if (!KVMODE) {
#pragma unroll
        for (int m = 0; m < 8; ++m) {
#pragma unroll
            for (int n = 0; n < 4; ++n) {
                const size_t col = nBase + wn * 64 + n * 16 + cx;
#pragma unroll
                for (int r = 0; r < 4; ++r) {
                    const size_t row = mBase + wm * 128 + m * 16 + rb4 + r;
                    storeC(&Cq[row * (size_t)ldc + col], acc[m][n][r]);
                }
            }
        }
    } else {
        // transposed write of K/V: KVt[b][h][i][s], via LDS (128KB) round-trip.
        __syncthreads();
        u16* T = &SM[0][0][0];
        const int nLoc = (int)(nBase & 1023);
#pragma unroll
        for (int n = 0; n < 4; ++n) {
            const int colL = wn * 64 + n * 16 + cx;
#pragma unroll
            for (int m = 0; m < 8; ++m) {
                const int R = wm * 128 + m * 16 + rb4;
                u16x4 v;
                v[0] = f2bf(acc[m][n][0]); v[1] = f2bf(acc[m][n][1]);
                v[2] = f2bf(acc[m][n][2]); v[3] = f2bf(acc[m][n][3]);
                const int byteoff = colL * 512 + ((((R >> 3) ^ (colL & 31)) << 4) | ((R & 7) << 1));
                *(u16x4*)((char*)T + byteoff) = v;
            }
        }
        __syncthreads();
        // coalesced store: half-wave (32 lanes) covers one full 512B row
        const int b = (int)(mBase >> 12);
        u16* KV = ((nBase >> 10) == 0 ? Kt : Vt);
        const int j = lane & 31;  // 16B unit within row
#pragma unroll
        for (int u = 0; u < 16; ++u) {
            const int iLoc = wid * 32 + u * 2 + (lane >> 5);
            const int byteoff = iLoc * 512 + ((j ^ (iLoc & 31)) << 4);
            const int gcol = nLoc + iLoc;
            u16* dst = KV + (((size_t)(b * 16 + (gcol >> 6)) * 64 + (gcol & 63)) << 12)
                          + (mBase & 4095) + j * 8;
            *(u16x8*)dst = *(const u16x8*)((char*)T + byteoff);
        }
    }
}

// ---------- 128x128 double-buffered bf16 gemm (bf16 out): C[m][n]=sum_k A[m][k]Bt[n][k]
__global__ __launch_bounds__(256, 2) void gemm128(
    const u16* __restrict__ A, int lda,
    const u16* __restrict__ Bt, int ldb,
    u16* __restrict__ C, int ldc, int K) {
    __shared__ u16 A2[2][128 * 64];
    __shared__ u16 B2[2][128 * 64];
    const int tid = threadIdx.x, w = tid >> 6, lane = tid & 63;
    const int wr = w >> 1, wc = w & 1;
    const size_t mBase = (size_t)blockIdx.y * 128;
    const size_t nBase = (size_t)blockIdx.x * 128;
    const int lr = lane >> 3;
    const int scol = ((lane & 7) ^ lr) * 8;

    auto stage = [&](int buf, int kt) {
#pragma unroll
        for (int c = 0; c < 2; ++c) {
            const u16* g = c ? Bt : A;
            const int ld = c ? ldb : lda;
            const size_t rb = c ? nBase : mBase;
            u16* lds = c ? B2[buf] : A2[buf];
#pragma unroll
            for (int jj = 0; jj < 4; ++jj) {
                const int rowL = jj * 32 + w * 8;
                async16(g + (rb + rowL + lr) * (size_t)ld + (size_t)kt * 64 + scol,
                        lds + rowL * 64);
            }
        }
    };

    const int frow = lane & 15;
    const int xs0 = ((lane >> 4) ^ (frow & 7)) * 8;
    const int xs1 = ((4 + (lane >> 4)) ^ (frow & 7)) * 8;
    f32x4 acc[4][4] = {};

    stage(0, 0);
    __syncthreads();
    const int nk = K >> 6;
    for (int kt = 0; kt < nk; ++kt) {
        const int cur = kt & 1;
        if (kt + 1 < nk) stage(cur ^ 1, kt + 1);
        bf16x8 bF[4][2];
#pragma unroll
        for (int n = 0; n < 4; ++n) {
            const int rB = (wc * 64 + n * 16 + frow) * 64;
            bF[n][0] = *(const bf16x8*)&B2[cur][rB + xs0];
            bF[n][1] = *(const bf16x8*)&B2[cur][rB + xs1];
        }
#pragma unroll
        for (int m = 0; m < 4; ++m) {
            const int rA = (wr * 64 + m * 16 + frow) * 64;
            bf16x8 a0 = *(const bf16x8*)&A2[cur][rA + xs0];
            bf16x8 a1 = *(const bf16x8*)&A2[cur][rA + xs1];
#pragma unroll
            for (int n = 0; n < 4; ++n) {
                acc[m][n] = __builtin_amdgcn_mfma_f32_16x16x32_bf16(a0, bF[n][0], acc[m][n], 0, 0, 0);
                acc[m][n] = __builtin_amdgcn_mfma_f32_16x16x32_bf16(a1, bF[n][1], acc[m][n], 0, 0, 0);
            }
        }
        __syncthreads();  // drains vmcnt+lgkmcnt: next tile staged & reads done
    }
    const int rb4 = (lane >> 4) * 4, cx = lane & 15;
#pragma unroll
    for (int m = 0; m < 4; ++m)
#pragma unroll
        for (int n = 0; n < 4; ++n) {
            const size_t col = nBase + wc * 64 + n * 16 + cx;
#pragma unroll
            for (int r = 0; r < 4; ++r)
                C[(mBase + wr * 64 + m * 16 + rb4 + r) * (size_t)ldc + col] = f2bf(acc[m][n][r]);
        }
}

// ---------- kv partial GEMM: P[chunk][bh][i][j] = sum_{s in chunk} Kt[i][s]*Vt[j][s] ----------
__global__ __launch_bounds__(256, 2) void kv_gemm(
    const u16* __restrict__ Kt, const u16* __restrict__ Vt, float* __restrict__ P) {
    __shared__ u16 Ks[64 * 64];
    __shared__ u16 Vs[64 * 64];
    const int chunk = blockIdx.x, bh = blockIdx.y;
    const int tid = threadIdx.x, w = tid >> 6, lane = tid & 63;
    const int srow = lane >> 3;
    const int scol = ((lane & 7) ^ srow) * 8;
    const int frow = lane & 15;
    const int xs0 = ((lane >> 4) ^ (frow & 7)) * 8;
    const int xs1 = ((4 + (lane >> 4)) ^ (frow & 7)) * 8;
    const size_t base = (size_t)bh * 64 * 4096 + (size_t)chunk * 512;
    f32x4 acc[4] = {};
    for (int kk = 0; kk < 8; ++kk) {
        __syncthreads();
#pragma unroll
        for (int j = 0; j < 2; ++j) {
            const int row = w * 16 + j * 8;
            async16(Kt + base + (size_t)(row + srow) * 4096 + kk * 64 + scol, &Ks[row * 64]);
            async16(Vt + base + (size_t)(row + srow) * 4096 + kk * 64 + scol, &Vs[row * 64]);
        }
        asm volatile("s_waitcnt vmcnt(0)" ::: "memory");
        __syncthreads();
        bf16x8 a0 = *(const bf16x8*)&Ks[(w * 16 + frow) * 64 + xs0];
        bf16x8 a1 = *(const bf16x8*)&Ks[(w * 16 + frow) * 64 + xs1];
#pragma unroll
        for (int n = 0; n < 4; ++n) {
            bf16x8 b0 = *(const bf16x8*)&Vs[(n * 16 + frow) * 64 + xs0];
            bf16x8 b1 = *(const bf16x8*)&Vs[(n * 16 + frow) * 64 + xs1];
            acc[n] = __builtin_amdgcn_mfma_f32_16x16x32_bf16(a0, b0, acc[n], 0, 0, 0);
            acc[n] = __builtin_amdgcn_mfma_f32_16x16x32_bf16(a1, b1, acc[n], 0, 0, 0);
        }
    }
    const int rb4 = (lane >> 4) * 4, cx = lane & 15;
    float* p = P + ((size_t)chunk * 64 + bh) * 4096;
#pragma unroll
    for (int n = 0; n < 4; ++n)
#pragma unroll
        for (int r = 0; r < 4; ++r)
            p[(w * 16 + rb4 + r) * 64 + n * 16 + cx] = acc[n][r];
}

// ---------- kv reduce over 8 chunks, apply scale, -> bf16 ----------
__global__ void kv_reduce(const float* __restrict__ P, u16* __restrict__ kvb) {
    const int bh = blockIdx.x, t = threadIdx.x;
    for (int idx = t; idx < 4096; idx += 256) {
        float s = 0.f;
#pragma unroll
        for (int c = 0; c < 8; ++c) s += P[((size_t)c * 64 + bh) * 4096 + idx];
        kvb[(size_t)bh * 4096 + idx] = f2bf(s * 0.125f);
    }
}

// ---------- W2t[b][e][h*64+i] = sum_j Wob[e][h*64+j] * kv[bh][i][j] ----------
__global__ __launch_bounds__(256, 2) void w2_gemm(
    const u16* __restrict__ Wob, const u16* __restrict__ kvb, u16* __restrict__ W2t) {
    __shared__ u16 Aw[256 * 64];
    __shared__ u16 Bw[64 * 64];
    const int eT = blockIdx.x, h = blockIdx.y, b = blockIdx.z;
    const int tid = threadIdx.x, w = tid >> 6, lane = tid & 63;
    const int srow = lane >> 3;
    const int scol = ((lane & 7) ^ srow) * 8;
#pragma unroll
    for (int j = 0; j < 8; ++j) {
        const int row = w * 64 + j * 8;
        async16(Wob + (size_t)(eT * 256 + row + srow) * 1024 + h * 64 + scol, &Aw[row * 64]);
    }
#pragma unroll
    for (int j = 0; j < 2; ++j) {
        const int row = w * 16 + j * 8;
        async16(kvb + ((size_t)(b * 16 + h) * 64 + row + srow) * 64 + scol, &Bw[row * 64]);
    }
    asm volatile("s_waitcnt vmcnt(0)" ::: "memory");
    __syncthreads();
    const int frow = lane & 15;
    const int xs0 = ((lane >> 4) ^ (frow & 7)) * 8;
    const int xs1 = ((4 + (lane >> 4)) ^ (frow & 7)) * 8;
    f32x4 acc[4][4] = {};
#pragma unroll
    for (int m = 0; m < 4; ++m) {
        bf16x8 a0 = *(const bf16x8*)&Aw[(w * 64 + m * 16 + frow) * 64 + xs0];
        bf16x8 a1 = *(const bf16x8*)&Aw[(w * 64 + m * 16 + frow) * 64 + xs1];
#pragma unroll
        for (int n = 0; n < 4; ++n) {
            bf16x8 b0 = *(const bf16x8*)&Bw[(n * 16 + frow) * 64 + xs0];
            bf16x8 b1 = *(const bf16x8*)&Bw[(n * 16 + frow) * 64 + xs1];
            acc[m][n] = __builtin_amdgcn_mfma_f32_16x16x32_bf16(a0, b0, acc[m][n], 0, 0, 0);
            acc[m][n] = __builtin_amdgcn_mfma_f32_16x16x32_bf16(a1, b1, acc[m][n], 0, 0, 0);
        }
    }
    const int rb4 = (lane >> 4) * 4, cx = lane & 15;
    u16* out = W2t + (size_t)b * 1048576;
#pragma unroll
    for (int m = 0; m < 4; ++m)
#pragma unroll
        for (int n = 0; n < 4; ++n)
#pragma unroll
            for (int r = 0; r < 4; ++r)
                out[(size_t)(eT * 256 + w * 64 + m * 16 + rb4 + r) * 1024 + h * 64 + n * 16 + cx] =
                    f2bf(acc[m][n][r]);
}

extern "C" void kernel_launch(void* const* d_in, const int* in_sizes, int n_in,
                              void* d_out, int out_size, void* d_ws, size_t ws_size,
                              hipStream_t stream) {
    const float* x  = (const float*)d_in[0];
    const float* Wq = (const float*)d_in[1];
    const float* Wk = (const float*)d_in[2];
    const float* Wv = (const float*)d_in[3];
    const float* Wo = (const float*)d_in[4];
    float* out = (float*)d_out;
    char* ws = (char*)d_ws;

    // workspace layout (bytes)
    u16*   xb    = (u16*)(ws);                    // [16384][1024] bf16   32 MB
    u16*   Kt    = (u16*)(ws + 33554432);         // [4][16][64][4096]    32 MB
    u16*   Vt    = (u16*)(ws + 67108864);         // [4][16][64][4096]    32 MB
    u16*   WkvT  = (u16*)(ws + 100663296);        // [2048][1024]  bf16    4 MB
    u16*   Wqb   = (u16*)(ws + 104857600);        // [1024][1024]  bf16    2 MB
    u16*   Wob   = (u16*)(ws + 106954752);        // [1024][1024]  bf16    2 MB
    float* Pkv   = (float*)(ws + 109051904);      // [8][64][64][64] f32   8 MB
    u16*   kvb   = (u16*)(ws + 117440512);        // [64][64][64] bf16   0.5 MB
    u16*   W2t   = (u16*)(ws + 117964800);        // [4][1024][1024] bf16  8 MB
    u16*   W3T   = (u16*)(ws + 126353408);        // [4][1024][1024] bf16  8 MB

    cvt_f32_bf16<<<8192, 256, 0, stream>>>(x, xb, 16777216L);
    cvt_f32_bf16<<<512, 256, 0, stream>>>(Wq, Wqb, 1048576L);
    cvt_f32_bf16<<<512, 256, 0, stream>>>(Wo, Wob, 1048576L);
    transpose_cvt<<<dim3(32, 32, 2), dim3(32, 8), 0, stream>>>(Wk, Wv, WkvT);

    // [Kt|Vt] = xb @ [Wk|Wv], written transposed; grid 8*64=512 (%8==0)
    gemm8p<u16, true><<<512, 512, 0, stream>>>(xb, 1024, WkvT, 1024, (u16*)nullptr, 0,
                                               1024, 8, 0, Kt, Vt);

    kv_gemm<<<dim3(8, 64), 256, 0, stream>>>(Kt, Vt, Pkv);
    kv_reduce<<<64, 256, 0, stream>>>(Pkv, kvb);
    w2_gemm<<<dim3(4, 16, 4), 256, 0, stream>>>(Wob, kvb, W2t);

    // W3T[b*1024+e][d] = sum_k W2t[b][e][k] * Wq[d][k]  (M=4096, N=1024, K=1024)
    gemm128<<<dim3(8, 32), 256, 0, stream>>>(W2t, 1024, Wqb, 1024, W3T, 1024, 1024);

    // out = xb @ W3T^T (per-batch Bt); grid 4*64=256 (%8==0)
    gemm8p<float, false><<<256, 512, 0, stream>>>(xb, 1024, W3T, 1024, out, 1024, 1024, 4,
                                                  1048576, nullptr, nullptr);
}

// Round 8
// 298.246 us; speedup vs baseline: 1.0056x; 1.0056x over previous
//
#include <hip/hip_runtime.h>

typedef unsigned short u16;
typedef unsigned int u32;
typedef u16 u16x8 __attribute__((ext_vector_type(8)));
typedef u16 u16x4 __attribute__((ext_vector_type(4)));
typedef __bf16 bf16x8 __attribute__((ext_vector_type(8)));
typedef float f32x4 __attribute__((ext_vector_type(4)));

// ---------- helpers ----------
__device__ __forceinline__ u16 f2bf(float f) {
    u32 u = __builtin_bit_cast(u32, f);
    u32 r = (u + 0x7fffu + ((u >> 16) & 1u)) >> 16;
    return (u16)r;
}
__device__ __forceinline__ void async16(const u16* g, u16* lds_base) {
    // HW writes lds_base + lane*16B; lds_base must be wave-uniform.
    __builtin_amdgcn_global_load_lds(
        (const __attribute__((address_space(1))) void*)g,
        (__attribute__((address_space(3))) void*)lds_base, 16, 0, 0);
}
__device__ __forceinline__ void storeC(float* p, float v) { *p = v; }
__device__ __forceinline__ void storeC(u16* p, float v)   { *p = f2bf(v); }

// ---------- fp32 -> bf16 convert (8 elems/thread) ----------
__global__ void cvt_f32_bf16(const float* __restrict__ in, u16* __restrict__ out, long n) {
    long idx = ((long)blockIdx.x * blockDim.x + threadIdx.x) * 8;
    if (idx >= n) return;
    float4 a = *(const float4*)(in + idx);
    float4 b = *(const float4*)(in + idx + 4);
    u16x8 o;
    o[0] = f2bf(a.x); o[1] = f2bf(a.y); o[2] = f2bf(a.z); o[3] = f2bf(a.w);
    o[4] = f2bf(b.x); o[5] = f2bf(b.y); o[6] = f2bf(b.z); o[7] = f2bf(b.w);
    *(u16x8*)(out + idx) = o;
}

// ---------- transpose+convert Wk/Wv -> WkvT [2048][1024] bf16 ----------
__global__ void transpose_cvt(const float* __restrict__ W0, const float* __restrict__ W1,
                              u16* __restrict__ WT) {
    __shared__ float tile[32][33];
    const float* W = (blockIdx.z == 0) ? W0 : W1;
    int n0 = blockIdx.x * 32, k0 = blockIdx.y * 32;
    int tx = threadIdx.x, ty = threadIdx.y;
#pragma unroll
    for (int r = 0; r < 4; ++r)
        tile[ty + 8 * r][tx] = W[(size_t)(k0 + ty + 8 * r) * 1024 + n0 + tx];
    __syncthreads();
#pragma unroll
    for (int r = 0; r < 4; ++r) {
        int n = n0 + ty + 8 * r;
        WT[((size_t)blockIdx.z * 1024 + n) * 1024 + k0 + tx] = f2bf(tile[tx][ty + 8 * r]);
    }
}

// ================= 256x256 pipelined bf16 MFMA GEMM (T2 swizzle, 1 barrier/phase) ====
// C[m][n] = sum_k A[m][k] * Bt[n][k].  K multiple of 128. M,N multiples of 256.
#define BAR __builtin_amdgcn_s_barrier()
#define SB0 __builtin_amdgcn_sched_barrier(0)
#define PRIO1 __builtin_amdgcn_s_setprio(1)
#define PRIO0 __builtin_amdgcn_s_setprio(0)
#define VM(n) asm volatile("s_waitcnt vmcnt(" #n ")" ::: "memory")

#define As SM[0]
#define Bs SM[1]

#define LDALO(buf) do { _Pragma("unroll") for (int mi = 0; mi < 4; ++mi) { \
    const int rA = (wm * 128 + mi * 16 + frow) * 64; \
    aLo[mi][0] = *(const bf16x8*)&As[buf][rA + xs0]; \
    aLo[mi][1] = *(const bf16x8*)&As[buf][rA + xs1]; } } while (0)

#define LDAHI(buf) do { _Pragma("unroll") for (int mi = 0; mi < 4; ++mi) { \
    const int rA = (wm * 128 + 64 + mi * 16 + frow) * 64; \
    aHi[mi][0] = *(const bf16x8*)&As[buf][rA + xs0]; \
    aHi[mi][1] = *(const bf16x8*)&As[buf][rA + xs1]; } } while (0)

#define LDBL(BL, buf) do { _Pragma("unroll") for (int ni = 0; ni < 2; ++ni) { \
    const int rB = (wn * 64 + ni * 16 + frow) * 64; \
    BL[ni][0] = *(const bf16x8*)&Bs[buf][rB + xs0]; \
    BL[ni][1] = *(const bf16x8*)&Bs[buf][rB + xs1]; } } while (0)

#define LDBHI(buf) do { _Pragma("unroll") for (int ni = 0; ni < 2; ++ni) { \
    const int rB = (wn * 64 + 32 + ni * 16 + frow) * 64; \
    bHi[ni][0] = *(const bf16x8*)&Bs[buf][rB + xs0]; \
    bHi[ni][1] = *(const bf16x8*)&Bs[buf][rB + xs1]; } } while (0)

#define MFQ00(BL) do { _Pragma("unroll") for (int mi = 0; mi < 4; ++mi) \
  _Pragma("unroll") for (int ni = 0; ni < 2; ++ni) \
  _Pragma("unroll") for (int s = 0; s < 2; ++s) \
    acc[mi][ni] = __builtin_amdgcn_mfma_f32_16x16x32_bf16(aLo[mi][s], BL[ni][s], acc[mi][ni], 0, 0, 0); } while (0)
#define MFQ01 do { _Pragma("unroll") for (int mi = 0; mi < 4; ++mi) \
  _Pragma("unroll") for (int ni = 0; ni < 2; ++ni) \
  _Pragma("unroll") for (int s = 0; s < 2; ++s) \
    acc[mi][2 + ni] = __builtin_amdgcn_mfma_f32_16x16x32_bf16(aLo[mi][s], bHi[ni][s], acc[mi][2 + ni], 0, 0, 0); } while (0)
#define MFQ11 do { _Pragma("unroll") for (int mi = 0; mi < 4; ++mi) \
  _Pragma("unroll") for (int ni = 0; ni < 2; ++ni) \
  _Pragma("unroll") for (int s = 0; s < 2; ++s) \
    acc[4 + mi][2 + ni] = __builtin_amdgcn_mfma_f32_16x16x32_bf16(aHi[mi][s], bHi[ni][s], acc[4 + mi][2 + ni], 0, 0, 0); } while (0)
#define MFQ10(BL) do { _Pragma("unroll") for (int mi = 0; mi < 4; ++mi) \
  _Pragma("unroll") for (int ni = 0; ni < 2; ++ni) \
  _Pragma("unroll") for (int s = 0; s < 2; ++s) \
    acc[4 + mi][ni] = __builtin_amdgcn_mfma_f32_16x16x32_bf16(aHi[mi][s], BL[ni][s], acc[4 + mi][ni], 0, 0, 0); } while (0)

// One K-tile, 4 phases, 1 barrier each. ds_reads issued one phase ahead;
// buf(t) restaged for t+2 at ph2/ph3/ph4 (gated by read-completion barriers);
// vmcnt(6)+BAR at ph3 guarantees buf(t+1) fully staged before ph4's lookahead reads.
#define TILEP(buf, BLC, BLN, stg, kt2, look) do { \
  LDBHI(buf); SB0; PRIO1; MFQ00(BLC); PRIO0; BAR; SB0; \
  LDAHI(buf); \
  if (stg) { stageH(buf, 0, 0, kt2); stageH(buf, 1, 0, kt2); } \
  SB0; PRIO1; MFQ01; PRIO0; BAR; SB0; \
  if (stg) stageH(buf, 1, 1, kt2); \
  SB0; PRIO1; MFQ11; PRIO0; \
  if (stg) { VM(6); } else { VM(0); } \
  BAR; SB0; \
  if (look) { LDALO((buf) ^ 1); LDBL(BLN, (buf) ^ 1); } \
  if (stg) stageH(buf, 0, 1, kt2); \
  SB0; PRIO1; MFQ10(BLC); PRIO0; BAR; SB0; \
} while (0)

// KVMODE=true: nBase 0-1023 -> Kt (transposed), 1024-2047 -> Vt (transposed).
// KVMODE=false: Bt += (mBase>>12)*btStrideB (per-batch B), normal C write.
// launch_bounds(512,1): LDS (128KB) already limits to 1 block/CU (2 waves/SIMD);
// min-waves=1 lifts the unified-reg cap 256->512 so the pipeline frags don't spill.
template <typename OutT, bool KVMODE>
__global__ __launch_bounds__(512, 1) void gemm8p(
    const u16* __restrict__ A, int lda,
    const u16* __restrict__ Bt, int ldb,
    OutT* __restrict__ Cq, int ldc, int K, int nTN,
    size_t btStrideB, u16* __restrict__ Kt, u16* __restrict__ Vt) {
    __shared__ u16 SM[2][2][256 * 64];
    const int tid = threadIdx.x;
    const int wid = tid >> 6, lane = tid & 63;
    const int wm = wid >> 2, wn = wid & 3;

    const int nwg = gridDim.x;
    const int orig = blockIdx.x;
    const int id = (orig & 7) * (nwg >> 3) + (orig >> 3);
    const size_t mBase = (size_t)(id / nTN) * 256;
    const size_t nBase = (size_t)(id % nTN) * 256;

    if (!KVMODE) Bt += (mBase >> 12) * btStrideB;

    const int srow = lane >> 3;
    const int scol = (((lane & 7) ^ (srow & 7)) * 8);

    auto stageH = [&](int buf, int isB, int h, int kt) {
        const u16* g = isB ? Bt : A;
        const int ld = isB ? ldb : lda;
        const size_t rb = isB ? nBase : mBase;
        u16* lds = isB ? Bs[buf] : As[buf];
#pragma unroll
        for (int j = 0; j < 2; ++j) {
            const int rowL = isB ? ((wid >> 1) * 64 + h * 32 + (wid & 1) * 16 + j * 8)
                                 : ((wid >> 2) * 128 + h * 64 + (wid & 3) * 16 + j * 8);
            async16(g + (rb + rowL + srow) * (size_t)ld + (size_t)kt * 64 + scol,
                    lds + rowL * 64);
        }
    };

    const int frow = lane & 15;
    const int xs0 = (((lane >> 4)) ^ (frow & 7)) * 8;
    const int xs1 = ((4 + (lane >> 4)) ^ (frow & 7)) * 8;

    f32x4 acc[8][4] = {};
    bf16x8 aLo[4][2], aHi[4][2], bL0[2][2], bL1[2][2], bHi[2][2];

    // prologue: stage tiles 0 and 1 fully, then pre-read tile-0's ph1 fragments
#pragma unroll
    for (int h = 0; h < 2; ++h) { stageH(0, 0, h, 0); stageH(0, 1, h, 0); }
#pragma unroll
    for (int h = 0; h < 2; ++h) { stageH(1, 0, h, 1); stageH(1, 1, h, 1); }
    VM(8);
    BAR; SB0;
    LDALO(0); LDBL(bL0, 0);

    const int nt = K >> 6;  // even, >= 4
    for (int t = 0; t < nt; t += 2) {
        TILEP(0, bL0, bL1, (t + 2 < nt), t + 2, true);
        TILEP(1, bL1, bL0, (t + 3 < nt), t + 3, (t + 2 < nt));
    }

    const int rb4 = (lane >> 4) * 4;
    const int cx = lane & 15;
    if (!KVMODE) {
#pragma unroll
        for (int m = 0; m < 8; ++m) {
#pragma unroll
            for (int n = 0; n < 4; ++n) {
                const size_t col = nBase + wn * 64 + n * 16 + cx;
#pragma unroll
                for (int r = 0; r < 4; ++r) {
                    const size_t row = mBase + wm * 128 + m * 16 + rb4 + r;
                    storeC(&Cq[row * (size_t)ldc + col], acc[m][n][r]);
                }
            }
        }
    } else {
        // transposed write of K/V: KVt[b][h][i][s], via LDS (128KB) round-trip.
        __syncthreads();
        u16* T = &SM[0][0][0];
        const int nLoc = (int)(nBase & 1023);
#pragma unroll
        for (int n = 0; n < 4; ++n) {
            const int colL = wn * 64 + n * 16 + cx;
#pragma unroll
            for (int m = 0; m < 8; ++m) {
                const int R = wm * 128 + m * 16 + rb4;
                u16x4 v;
                v[0] = f2bf(acc[m][n][0]); v[1] = f2bf(acc[m][n][1]);
                v[2] = f2bf(acc[m][n][2]); v[3] = f2bf(acc[m][n][3]);
                const int byteoff = colL * 512 + ((((R >> 3) ^ (colL & 31)) << 4) | ((R & 7) << 1));
                *(u16x4*)((char*)T + byteoff) = v;
            }
        }
        __syncthreads();
        // coalesced store: half-wave (32 lanes) covers one full 512B row
        const int b = (int)(mBase >> 12);
        u16* KV = ((nBase >> 10) == 0 ? Kt : Vt);
        const int j = lane & 31;  // 16B unit within row
#pragma unroll
        for (int u = 0; u < 16; ++u) {
            const int iLoc = wid * 32 + u * 2 + (lane >> 5);
            const int byteoff = iLoc * 512 + ((j ^ (iLoc & 31)) << 4);
            const int gcol = nLoc + iLoc;
            u16* dst = KV + (((size_t)(b * 16 + (gcol >> 6)) * 64 + (gcol & 63)) << 12)
                          + (mBase & 4095) + j * 8;
            *(u16x8*)dst = *(const u16x8*)((char*)T + byteoff);
        }
    }
}

// ---------- 128x128 double-buffered bf16 gemm (bf16 out): C[m][n]=sum_k A[m][k]Bt[n][k]
__global__ __launch_bounds__(256, 2) void gemm128(
    const u16* __restrict__ A, int lda,
    const u16* __restrict__ Bt, int ldb,
    u16* __restrict__ C, int ldc, int K) {
    __shared__ u16 A2[2][128 * 64];
    __shared__ u16 B2[2][128 * 64];
    const int tid = threadIdx.x, w = tid >> 6, lane = tid & 63;
    const int wr = w >> 1, wc = w & 1;
    const size_t mBase = (size_t)blockIdx.y * 128;
    const size_t nBase = (size_t)blockIdx.x * 128;
    const int lr = lane >> 3;
    const int scol = ((lane & 7) ^ lr) * 8;

    auto stage = [&](int buf, int kt) {
#pragma unroll
        for (int c = 0; c < 2; ++c) {
            const u16* g = c ? Bt : A;
            const int ld = c ? ldb : lda;
            const size_t rb = c ? nBase : mBase;
            u16* lds = c ? B2[buf] : A2[buf];
#pragma unroll
            for (int jj = 0; jj < 4; ++jj) {
                const int rowL = jj * 32 + w * 8;
                async16(g + (rb + rowL + lr) * (size_t)ld + (size_t)kt * 64 + scol,
                        lds + rowL * 64);
            }
        }
    };

    const int frow = lane & 15;
    const int xs0 = ((lane >> 4) ^ (frow & 7)) * 8;
    const int xs1 = ((4 + (lane >> 4)) ^ (frow & 7)) * 8;
    f32x4 acc[4][4] = {};

    stage(0, 0);
    __syncthreads();
    const int nk = K >> 6;
    for (int kt = 0; kt < nk; ++kt) {
        const int cur = kt & 1;
        if (kt + 1 < nk) stage(cur ^ 1, kt + 1);
        bf16x8 bF[4][2];
#pragma unroll
        for (int n = 0; n < 4; ++n) {
            const int rB = (wc * 64 + n * 16 + frow) * 64;
            bF[n][0] = *(const bf16x8*)&B2[cur][rB + xs0];
            bF[n][1] = *(const bf16x8*)&B2[cur][rB + xs1];
        }
#pragma unroll
        for (int m = 0; m < 4; ++m) {
            const int rA = (wr * 64 + m * 16 + frow) * 64;
            bf16x8 a0 = *(const bf16x8*)&A2[cur][rA + xs0];
            bf16x8 a1 = *(const bf16x8*)&A2[cur][rA + xs1];
#pragma unroll
            for (int n = 0; n < 4; ++n) {
                acc[m][n] = __builtin_amdgcn_mfma_f32_16x16x32_bf16(a0, bF[n][0], acc[m][n], 0, 0, 0);
                acc[m][n] = __builtin_amdgcn_mfma_f32_16x16x32_bf16(a1, bF[n][1], acc[m][n], 0, 0, 0);
            }
        }
        __syncthreads();  // drains vmcnt+lgkmcnt: next tile staged & reads done
    }
    const int rb4 = (lane >> 4) * 4, cx = lane & 15;
#pragma unroll
    for (int m = 0; m < 4; ++m)
#pragma unroll
        for (int n = 0; n < 4; ++n) {
            const size_t col = nBase + wc * 64 + n * 16 + cx;
#pragma unroll
            for (int r = 0; r < 4; ++r)
                C[(mBase + wr * 64 + m * 16 + rb4 + r) * (size_t)ldc + col] = f2bf(acc[m][n][r]);
        }
}

// ---------- kv partial GEMM: P[chunk][bh][i][j] = sum_{s in chunk} Kt[i][s]*Vt[j][s] ----------
__global__ __launch_bounds__(256, 2) void kv_gemm(
    const u16* __restrict__ Kt, const u16* __restrict__ Vt, float* __restrict__ P) {
    __shared__ u16 Ks[64 * 64];
    __shared__ u16 Vs[64 * 64];
    const int chunk = blockIdx.x, bh = blockIdx.y;
    const int tid = threadIdx.x, w = tid >> 6, lane = tid & 63;
    const int srow = lane >> 3;
    const int scol = ((lane & 7) ^ srow) * 8;
    const int frow = lane & 15;
    const int xs0 = ((lane >> 4) ^ (frow & 7)) * 8;
    const int xs1 = ((4 + (lane >> 4)) ^ (frow & 7)) * 8;
    const size_t base = (size_t)bh * 64 * 4096 + (size_t)chunk * 512;
    f32x4 acc[4] = {};
    for (int kk = 0; kk < 8; ++kk) {
        __syncthreads();
#pragma unroll
        for (int j = 0; j < 2; ++j) {
            const int row = w * 16 + j * 8;
            async16(Kt + base + (size_t)(row + srow) * 4096 + kk * 64 + scol, &Ks[row * 64]);
            async16(Vt + base + (size_t)(row + srow) * 4096 + kk * 64 + scol, &Vs[row * 64]);
        }
        asm volatile("s_waitcnt vmcnt(0)" ::: "memory");
        __syncthreads();
        bf16x8 a0 = *(const bf16x8*)&Ks[(w * 16 + frow) * 64 + xs0];
        bf16x8 a1 = *(const bf16x8*)&Ks[(w * 16 + frow) * 64 + xs1];
#pragma unroll
        for (int n = 0; n < 4; ++n) {
            bf16x8 b0 = *(const bf16x8*)&Vs[(n * 16 + frow) * 64 + xs0];
            bf16x8 b1 = *(const bf16x8*)&Vs[(n * 16 + frow) * 64 + xs1];
            acc[n] = __builtin_amdgcn_mfma_f32_16x16x32_bf16(a0, b0, acc[n], 0, 0, 0);
            acc[n] = __builtin_amdgcn_mfma_f32_16x16x32_bf16(a1, b1, acc[n], 0, 0, 0);
        }
    }
    const int rb4 = (lane >> 4) * 4, cx = lane & 15;
    float* p = P + ((size_t)chunk * 64 + bh) * 4096;
#pragma unroll
    for (int n = 0; n < 4; ++n)
#pragma unroll
        for (int r = 0; r < 4; ++r)
            p[(w * 16 + rb4 + r) * 64 + n * 16 + cx] = acc[n][r];
}

// ---------- kv reduce over 8 chunks, apply scale, -> bf16 ----------
__global__ void kv_reduce(const float* __restrict__ P, u16* __restrict__ kvb) {
    const int bh = blockIdx.x, t = threadIdx.x;
    for (int idx = t; idx < 4096; idx += 256) {
        float s = 0.f;
#pragma unroll
        for (int c = 0; c < 8; ++c) s += P[((size_t)c * 64 + bh) * 4096 + idx];
        kvb[(size_t)bh * 4096 + idx] = f2bf(s * 0.125f);
    }
}

// ---------- W2t[b][e][h*64+i] = sum_j Wob[e][h*64+j] * kv[bh][i][j] ----------
__global__ __launch_bounds__(256, 2) void w2_gemm(
    const u16* __restrict__ Wob, const u16* __restrict__ kvb, u16* __restrict__ W2t) {
    __shared__ u16 Aw[256 * 64];
    __shared__ u16 Bw[64 * 64];
    const int eT = blockIdx.x, h = blockIdx.y, b = blockIdx.z;
    const int tid = threadIdx.x, w = tid >> 6, lane = tid & 63;
    const int srow = lane >> 3;
    const int scol = ((lane & 7) ^ srow) * 8;
#pragma unroll
    for (int j = 0; j < 8; ++j) {
        const int row = w * 64 + j * 8;
        async16(Wob + (size_t)(eT * 256 + row + srow) * 1024 + h * 64 + scol, &Aw[row * 64]);
    }
#pragma unroll
    for (int j = 0; j < 2; ++j) {
        const int row = w * 16 + j * 8;
        async16(kvb + ((size_t)(b * 16 + h) * 64 + row + srow) * 64 + scol, &Bw[row * 64]);
    }
    asm volatile("s_waitcnt vmcnt(0)" ::: "memory");
    __syncthreads();
    const int frow = lane & 15;
    const int xs0 = ((lane >> 4) ^ (frow & 7)) * 8;
    const int xs1 = ((4 + (lane >> 4)) ^ (frow & 7)) * 8;
    f32x4 acc[4][4] = {};
#pragma unroll
    for (int m = 0; m < 4; ++m) {
        bf16x8 a0 = *(const bf16x8*)&Aw[(w * 64 + m * 16 + frow) * 64 + xs0];
        bf16x8 a1 = *(const bf16x8*)&Aw[(w * 64 + m * 16 + frow) * 64 + xs1];
#pragma unroll
        for (int n = 0; n < 4; ++n) {
            bf16x8 b0 = *(const bf16x8*)&Bw[(n * 16 + frow) * 64 + xs0];
            bf16x8 b1 = *(const bf16x8*)&Bw[(n * 16 + frow) * 64 + xs1];
            acc[m][n] = __builtin_amdgcn_mfma_f32_16x16x32_bf16(a0, b0, acc[m][n], 0, 0, 0);
            acc[m][n] = __builtin_amdgcn_mfma_f32_16x16x32_bf16(a1, b1, acc[m][n], 0, 0, 0);
        }
    }
    const int rb4 = (lane >> 4) * 4, cx = lane & 15;
    u16* out = W2t + (size_t)b * 1048576;
#pragma unroll
    for (int m = 0; m < 4; ++m)
#pragma unroll
        for (int n = 0; n < 4; ++n)
#pragma unroll
            for (int r = 0; r < 4; ++r)
                out[(size_t)(eT * 256 + w * 64 + m * 16 + rb4 + r) * 1024 + h * 64 + n * 16 + cx] =
                    f2bf(acc[m][n][r]);
}

extern "C" void kernel_launch(void* const* d_in, const int* in_sizes, int n_in,
                              void* d_out, int out_size, void* d_ws, size_t ws_size,
                              hipStream_t stream) {
    const float* x  = (const float*)d_in[0];
    const float* Wq = (const float*)d_in[1];
    const float* Wk = (const float*)d_in[2];
    const float* Wv = (const float*)d_in[3];
    const float* Wo = (const float*)d_in[4];
    float* out = (float*)d_out;
    char* ws = (char*)d_ws;

    // workspace layout (bytes)
    u16*   xb    = (u16*)(ws);                    // [16384][1024] bf16   32 MB
    u16*   Kt    = (u16*)(ws + 33554432);         // [4][16][64][4096]    32 MB
    u16*   Vt    = (u16*)(ws + 67108864);         // [4][16][64][4096]    32 MB
    u16*   WkvT  = (u16*)(ws + 100663296);        // [2048][1024]  bf16    4 MB
    u16*   Wqb   = (u16*)(ws + 104857600);        // [1024][1024]  bf16    2 MB
    u16*   Wob   = (u16*)(ws + 106954752);        // [1024][1024]  bf16    2 MB
    float* Pkv   = (float*)(ws + 109051904);      // [8][64][64][64] f32   8 MB
    u16*   kvb   = (u16*)(ws + 117440512);        // [64][64][64] bf16   0.5 MB
    u16*   W2t   = (u16*)(ws + 117964800);        // [4][1024][1024] bf16  8 MB
    u16*   W3T   = (u16*)(ws + 126353408);        // [4][1024][1024] bf16  8 MB

    cvt_f32_bf16<<<8192, 256, 0, stream>>>(x, xb, 16777216L);
    cvt_f32_bf16<<<512, 256, 0, stream>>>(Wq, Wqb, 1048576L);
    cvt_f32_bf16<<<512, 256, 0, stream>>>(Wo, Wob, 1048576L);
    transpose_cvt<<<dim3(32, 32, 2), dim3(32, 8), 0, stream>>>(Wk, Wv, WkvT);

    // [Kt|Vt] = xb @ [Wk|Wv], written transposed; grid 8*64=512 (%8==0)
    gemm8p<u16, true><<<512, 512, 0, stream>>>(xb, 1024, WkvT, 1024, (u16*)nullptr, 0,
                                               1024, 8, 0, Kt, Vt);

    kv_gemm<<<dim3(8, 64), 256, 0, stream>>>(Kt, Vt, Pkv);
    kv_reduce<<<64, 256, 0, stream>>>(Pkv, kvb);
    w2_gemm<<<dim3(4, 16, 4), 256, 0, stream>>>(Wob, kvb, W2t);

    // W3T[b*1024+e][d] = sum_k W2t[b][e][k] * Wq[d][k]  (M=4096, N=1024, K=1024)
    gemm128<<<dim3(8, 32), 256, 0, stream>>>(W2t, 1024, Wqb, 1024, W3T, 1024, 1024);

    // out = xb @ W3T^T (per-batch Bt); grid 4*64=256 (%8==0)
    gemm8p<float, false><<<256, 512, 0, stream>>>(xb, 1024, W3T, 1024, out, 1024, 1024, 4,
                                                  1048576, nullptr, nullptr);
}

// Round 9
// 173.641 us; speedup vs baseline: 1.7273x; 1.7176x over previous
//
#include <hip/hip_runtime.h>

typedef unsigned short u16;
typedef unsigned int u32;
typedef u16 u16x8 __attribute__((ext_vector_type(8)));
typedef u16 u16x4 __attribute__((ext_vector_type(4)));
typedef __bf16 bf16x8 __attribute__((ext_vector_type(8)));
typedef float f32x4 __attribute__((ext_vector_type(4)));

// ---------- helpers ----------
__device__ __forceinline__ u16 f2bf(float f) {
    u32 u = __builtin_bit_cast(u32, f);
    u32 r = (u + 0x7fffu + ((u >> 16) & 1u)) >> 16;
    return (u16)r;
}
__device__ __forceinline__ void async16(const u16* g, u16* lds_base) {
    // HW writes lds_base + lane*16B; lds_base must be wave-uniform.
    __builtin_amdgcn_global_load_lds(
        (const __attribute__((address_space(1))) void*)g,
        (__attribute__((address_space(3))) void*)lds_base, 16, 0, 0);
}
__device__ __forceinline__ void storeC(float* p, float v) { *p = v; }
__device__ __forceinline__ void storeC(u16* p, float v)   { *p = f2bf(v); }

// ---------- fused fp32 -> bf16 convert for x, Wq, Wo (one launch) ----------
__global__ void cvt3_f32_bf16(const float* __restrict__ x, u16* __restrict__ xb,
                              const float* __restrict__ wq, u16* __restrict__ wqb,
                              const float* __restrict__ wo, u16* __restrict__ wob) {
    const int bid = blockIdx.x;
    const float* src; u16* dst; long base;
    if (bid < 8192)      { src = x;  dst = xb;  base = bid; }
    else if (bid < 8704) { src = wq; dst = wqb; base = bid - 8192; }
    else                 { src = wo; dst = wob; base = bid - 8704; }
    const long idx = (base * 256 + threadIdx.x) * 8;
    float4 a = *(const float4*)(src + idx);
    float4 b = *(const float4*)(src + idx + 4);
    u16x8 o;
    o[0] = f2bf(a.x); o[1] = f2bf(a.y); o[2] = f2bf(a.z); o[3] = f2bf(a.w);
    o[4] = f2bf(b.x); o[5] = f2bf(b.y); o[6] = f2bf(b.z); o[7] = f2bf(b.w);
    *(u16x8*)(dst + idx) = o;
}

// ---------- transpose+convert Wk/Wv -> WkvT [2048][1024] bf16 ----------
__global__ void transpose_cvt(const float* __restrict__ W0, const float* __restrict__ W1,
                              u16* __restrict__ WT) {
    __shared__ float tile[32][33];
    const float* W = (blockIdx.z == 0) ? W0 : W1;
    int n0 = blockIdx.x * 32, k0 = blockIdx.y * 32;
    int tx = threadIdx.x, ty = threadIdx.y;
#pragma unroll
    for (int r = 0; r < 4; ++r)
        tile[ty + 8 * r][tx] = W[(size_t)(k0 + ty + 8 * r) * 1024 + n0 + tx];
    __syncthreads();
#pragma unroll
    for (int r = 0; r < 4; ++r) {
        int n = n0 + ty + 8 * r;
        WT[((size_t)blockIdx.z * 1024 + n) * 1024 + k0 + tx] = f2bf(tile[tx][ty + 8 * r]);
    }
}

// ================= 256x256 pipelined bf16 MFMA GEMM (T2 swizzle, R6 schedule) ====
// C[m][n] = sum_k A[m][k] * Bt[n][k].  K multiple of 128. M,N multiples of 256.
#define BAR __builtin_amdgcn_s_barrier()
#define WAITLGK do { asm volatile("s_waitcnt lgkmcnt(0)" ::: "memory"); \
                     __builtin_amdgcn_sched_barrier(0); } while (0)
#define PRIO1 __builtin_amdgcn_s_setprio(1)
#define PRIO0 __builtin_amdgcn_s_setprio(0)
#define VM(n) asm volatile("s_waitcnt vmcnt(" #n ")" ::: "memory")

#define As SM[0]
#define Bs SM[1]

#define LDA(buf, mh) do { _Pragma("unroll") for (int mi = 0; mi < 4; ++mi) { \
    const int rA = (wm * 128 + (mh) * 64 + mi * 16 + frow) * 64; \
    aF[mi][0] = *(const bf16x8*)&As[buf][rA + xs0]; \
    aF[mi][1] = *(const bf16x8*)&As[buf][rA + xs1]; } } while (0)

#define LDB(buf, nh) do { _Pragma("unroll") for (int ni = 0; ni < 2; ++ni) { \
    const int rB = (wn * 64 + (nh) * 32 + ni * 16 + frow) * 64; \
    bF[(nh) * 2 + ni][0] = *(const bf16x8*)&Bs[buf][rB + xs0]; \
    bF[(nh) * 2 + ni][1] = *(const bf16x8*)&Bs[buf][rB + xs1]; } } while (0)

#define MFQ(mh, nh) do { _Pragma("unroll") for (int mi = 0; mi < 4; ++mi) \
  _Pragma("unroll") for (int ni = 0; ni < 2; ++ni) \
  _Pragma("unroll") for (int s = 0; s < 2; ++s) \
    acc[(mh) * 4 + mi][(nh) * 2 + ni] = __builtin_amdgcn_mfma_f32_16x16x32_bf16( \
        aF[mi][s], bF[(nh) * 2 + ni][s], acc[(mh) * 4 + mi][(nh) * 2 + ni], 0, 0, 0); } while (0)

// Phase k: {ds_read ; stage-issue ; BAR ; lgkmcnt(0) ; MFMA ; [vmcnt] ; BAR}
// Region read-completion: A-mh0/B-nh0 done after phase 1, B-nh1 after 2, A-mh1 after 3
// -> restage same buffer at phases 2 (Amh0+Bnh0), 3 (Bnh1), 4 (Amh1).
#define TILE4(buf, S1, S2, S3, S4, WV) \
  LDA(buf, 0); LDB(buf, 0); S1; BAR; WAITLGK; PRIO1; MFQ(0, 0); PRIO0; BAR; \
  LDB(buf, 1); S2; BAR; WAITLGK; PRIO1; MFQ(0, 1); PRIO0; BAR; \
  LDA(buf, 1); S3; BAR; WAITLGK; PRIO1; MFQ(1, 1); PRIO0; BAR; \
  S4; BAR; WAITLGK; PRIO1; MFQ(1, 0); PRIO0; WV; BAR;

// KVMODE=true: nBase 0-1023 -> Kt (transposed), 1024-2047 -> Vt (transposed).
// KVMODE=false: Bt += (mBase>>12)*btStrideB (per-batch B), normal C write.
// NOTE: LDS 128KB -> 1 block/CU (8 waves) -> unified reg budget is a HARD
// 256/wave (acc 128 AGPR + <=128 VGPR). The R6 fragment set (64 regs) fits;
// deeper cross-phase lookahead (R7) spills structurally. Keep this schedule.
template <typename OutT, bool KVMODE>
__global__ __launch_bounds__(512, 2) void gemm8p(
    const u16* __restrict__ A, int lda,
    const u16* __restrict__ Bt, int ldb,
    OutT* __restrict__ Cq, int ldc, int K, int nTN,
    size_t btStrideB, u16* __restrict__ Kt, u16* __restrict__ Vt) {
    __shared__ u16 SM[2][2][256 * 64];
    const int tid = threadIdx.x;
    const int wid = tid >> 6, lane = tid & 63;
    const int wm = wid >> 2, wn = wid & 3;

    const int nwg = gridDim.x;
    const int orig = blockIdx.x;
    const int id = (orig & 7) * (nwg >> 3) + (orig >> 3);
    const size_t mBase = (size_t)(id / nTN) * 256;
    const size_t nBase = (size_t)(id % nTN) * 256;

    if (!KVMODE) Bt += (mBase >> 12) * btStrideB;

    const int srow = lane >> 3;
    const int scol = (((lane & 7) ^ (srow & 7)) * 8);

    auto stageH = [&](int buf, int isB, int h, int kt) {
        const u16* g = isB ? Bt : A;
        const int ld = isB ? ldb : lda;
        const size_t rb = isB ? nBase : mBase;
        u16* lds = isB ? Bs[buf] : As[buf];
#pragma unroll
        for (int j = 0; j < 2; ++j) {
            const int rowL = isB ? ((wid >> 1) * 64 + h * 32 + (wid & 1) * 16 + j * 8)
                                 : ((wid >> 2) * 128 + h * 64 + (wid & 3) * 16 + j * 8);
            async16(g + (rb + rowL + srow) * (size_t)ld + (size_t)kt * 64 + scol,
                    lds + rowL * 64);
        }
    };

    const int frow = lane & 15;
    const int xs0 = (((lane >> 4)) ^ (frow & 7)) * 8;
    const int xs1 = ((4 + (lane >> 4)) ^ (frow & 7)) * 8;

    f32x4 acc[8][4] = {};
    bf16x8 aF[4][2], bF[4][2];

    // prologue: stage tiles 0 and 1 fully
#pragma unroll
    for (int h = 0; h < 2; ++h) { stageH(0, 0, h, 0); stageH(0, 1, h, 0); }
#pragma unroll
    for (int h = 0; h < 2; ++h) { stageH(1, 0, h, 1); stageH(1, 1, h, 1); }
    VM(8);
    BAR;

    const int np = K >> 7;
    for (int p = 0; p < np - 1; ++p) {
        const int k2 = 2 * p + 2, k3 = 2 * p + 3;
        TILE4(0, ,
              { stageH(0, 0, 0, k2); stageH(0, 1, 0, k2); },
              stageH(0, 1, 1, k2),
              stageH(0, 0, 1, k2),
              VM(8));
        TILE4(1, ,
              { stageH(1, 0, 0, k3); stageH(1, 1, 0, k3); },
              stageH(1, 1, 1, k3),
              stageH(1, 0, 1, k3),
              VM(8));
    }
    TILE4(0, , , , , VM(0));
    TILE4(1, , , , , );

    const int rb4 = (lane >> 4) * 4;
    const int cx = lane & 15;
    if (!KVMODE) {
#pragma unroll
        for (int m = 0; m < 8; ++m) {
#pragma unroll
            for (int n = 0; n < 4; ++n) {
                const size_t col = nBase + wn * 64 + n * 16 + cx;
#pragma unroll
                for (int r = 0; r < 4; ++r) {
                    const size_t row = mBase + wm * 128 + m * 16 + rb4 + r;
                    storeC(&Cq[row * (size_t)ldc + col], acc[m][n][r]);
                }
            }
        }
    } else {
        // transposed write of K/V: KVt[b][h][i][s], via LDS (128KB) round-trip.
        __syncthreads();
        u16* T = &SM[0][0][0];
        const int nLoc = (int)(nBase & 1023);
#pragma unroll
        for (int n = 0; n < 4; ++n) {
            const int colL = wn * 64 + n * 16 + cx;
#pragma unroll
            for (int m = 0; m < 8; ++m) {
                const int R = wm * 128 + m * 16 + rb4;
                u16x4 v;
                v[0] = f2bf(acc[m][n][0]); v[1] = f2bf(acc[m][n][1]);
                v[2] = f2bf(acc[m][n][2]); v[3] = f2bf(acc[m][n][3]);
                const int byteoff = colL * 512 + ((((R >> 3) ^ (colL & 31)) << 4) | ((R & 7) << 1));
                *(u16x4*)((char*)T + byteoff) = v;
            }
        }
        __syncthreads();
        // coalesced store: half-wave (32 lanes) covers one full 512B row
        const int b = (int)(mBase >> 12);
        u16* KV = ((nBase >> 10) == 0 ? Kt : Vt);
        const int j = lane & 31;  // 16B unit within row
#pragma unroll
        for (int u = 0; u < 16; ++u) {
            const int iLoc = wid * 32 + u * 2 + (lane >> 5);
            const int byteoff = iLoc * 512 + ((j ^ (iLoc & 31)) << 4);
            const int gcol = nLoc + iLoc;
            u16* dst = KV + (((size_t)(b * 16 + (gcol >> 6)) * 64 + (gcol & 63)) << 12)
                          + (mBase & 4095) + j * 8;
            *(u16x8*)dst = *(const u16x8*)((char*)T + byteoff);
        }
    }
}

// ---------- 128x128 double-buffered bf16 gemm (bf16 out): C[m][n]=sum_k A[m][k]Bt[n][k]
__global__ __launch_bounds__(256, 2) void gemm128(
    const u16* __restrict__ A, int lda,
    const u16* __restrict__ Bt, int ldb,
    u16* __restrict__ C, int ldc, int K) {
    __shared__ u16 A2[2][128 * 64];
    __shared__ u16 B2[2][128 * 64];
    const int tid = threadIdx.x, w = tid >> 6, lane = tid & 63;
    const int wr = w >> 1, wc = w & 1;
    const size_t mBase = (size_t)blockIdx.y * 128;
    const size_t nBase = (size_t)blockIdx.x * 128;
    const int lr = lane >> 3;
    const int scol = ((lane & 7) ^ lr) * 8;

    auto stage = [&](int buf, int kt) {
#pragma unroll
        for (int c = 0; c < 2; ++c) {
            const u16* g = c ? Bt : A;
            const int ld = c ? ldb : lda;
            const size_t rb = c ? nBase : mBase;
            u16* lds = c ? B2[buf] : A2[buf];
#pragma unroll
            for (int jj = 0; jj < 4; ++jj) {
                const int rowL = jj * 32 + w * 8;
                async16(g + (rb + rowL + lr) * (size_t)ld + (size_t)kt * 64 + scol,
                        lds + rowL * 64);
            }
        }
    };

    const int frow = lane & 15;
    const int xs0 = ((lane >> 4) ^ (frow & 7)) * 8;
    const int xs1 = ((4 + (lane >> 4)) ^ (frow & 7)) * 8;
    f32x4 acc[4][4] = {};

    stage(0, 0);
    __syncthreads();
    const int nk = K >> 6;
    for (int kt = 0; kt < nk; ++kt) {
        const int cur = kt & 1;
        if (kt + 1 < nk) stage(cur ^ 1, kt + 1);
        bf16x8 bF[4][2];
#pragma unroll
        for (int n = 0; n < 4; ++n) {
            const int rB = (wc * 64 + n * 16 + frow) * 64;
            bF[n][0] = *(const bf16x8*)&B2[cur][rB + xs0];
            bF[n][1] = *(const bf16x8*)&B2[cur][rB + xs1];
        }
#pragma unroll
        for (int m = 0; m < 4; ++m) {
            const int rA = (wr * 64 + m * 16 + frow) * 64;
            bf16x8 a0 = *(const bf16x8*)&A2[cur][rA + xs0];
            bf16x8 a1 = *(const bf16x8*)&A2[cur][rA + xs1];
#pragma unroll
            for (int n = 0; n < 4; ++n) {
                acc[m][n] = __builtin_amdgcn_mfma_f32_16x16x32_bf16(a0, bF[n][0], acc[m][n], 0, 0, 0);
                acc[m][n] = __builtin_amdgcn_mfma_f32_16x16x32_bf16(a1, bF[n][1], acc[m][n], 0, 0, 0);
            }
        }
        __syncthreads();  // drains vmcnt+lgkmcnt: next tile staged & reads done
    }
    const int rb4 = (lane >> 4) * 4, cx = lane & 15;
#pragma unroll
    for (int m = 0; m < 4; ++m)
#pragma unroll
        for (int n = 0; n < 4; ++n) {
            const size_t col = nBase + wc * 64 + n * 16 + cx;
#pragma unroll
            for (int r = 0; r < 4; ++r)
                C[(mBase + wr * 64 + m * 16 + rb4 + r) * (size_t)ldc + col] = f2bf(acc[m][n][r]);
        }
}

// ---------- kv partial GEMM: P[chunk][bh][i][j] = sum_{s in chunk} Kt[i][s]*Vt[j][s] ----------
__global__ __launch_bounds__(256, 2) void kv_gemm(
    const u16* __restrict__ Kt, const u16* __restrict__ Vt, float* __restrict__ P) {
    __shared__ u16 Ks[64 * 64];
    __shared__ u16 Vs[64 * 64];
    const int chunk = blockIdx.x, bh = blockIdx.y;
    const int tid = threadIdx.x, w = tid >> 6, lane = tid & 63;
    const int srow = lane >> 3;
    const int scol = ((lane & 7) ^ srow) * 8;
    const int frow = lane & 15;
    const int xs0 = ((lane >> 4) ^ (frow & 7)) * 8;
    const int xs1 = ((4 + (lane >> 4)) ^ (frow & 7)) * 8;
    const size_t base = (size_t)bh * 64 * 4096 + (size_t)chunk * 512;
    f32x4 acc[4] = {};
    for (int kk = 0; kk < 8; ++kk) {
        __syncthreads();
#pragma unroll
        for (int j = 0; j < 2; ++j) {
            const int row = w * 16 + j * 8;
            async16(Kt + base + (size_t)(row + srow) * 4096 + kk * 64 + scol, &Ks[row * 64]);
            async16(Vt + base + (size_t)(row + srow) * 4096 + kk * 64 + scol, &Vs[row * 64]);
        }
        asm volatile("s_waitcnt vmcnt(0)" ::: "memory");
        __syncthreads();
        bf16x8 a0 = *(const bf16x8*)&Ks[(w * 16 + frow) * 64 + xs0];
        bf16x8 a1 = *(const bf16x8*)&Ks[(w * 16 + frow) * 64 + xs1];
#pragma unroll
        for (int n = 0; n < 4; ++n) {
            bf16x8 b0 = *(const bf16x8*)&Vs[(n * 16 + frow) * 64 + xs0];
            bf16x8 b1 = *(const bf16x8*)&Vs[(n * 16 + frow) * 64 + xs1];
            acc[n] = __builtin_amdgcn_mfma_f32_16x16x32_bf16(a0, b0, acc[n], 0, 0, 0);
            acc[n] = __builtin_amdgcn_mfma_f32_16x16x32_bf16(a1, b1, acc[n], 0, 0, 0);
        }
    }
    const int rb4 = (lane >> 4) * 4, cx = lane & 15;
    float* p = P + ((size_t)chunk * 64 + bh) * 4096;
#pragma unroll
    for (int n = 0; n < 4; ++n)
#pragma unroll
        for (int r = 0; r < 4; ++r)
            p[(w * 16 + rb4 + r) * 64 + n * 16 + cx] = acc[n][r];
}

// ---------- kv reduce over 8 chunks, apply scale, -> bf16 ----------
__global__ void kv_reduce(const float* __restrict__ P, u16* __restrict__ kvb) {
    const int bh = blockIdx.x, t = threadIdx.x;
    for (int idx = t; idx < 4096; idx += 256) {
        float s = 0.f;
#pragma unroll
        for (int c = 0; c < 8; ++c) s += P[((size_t)c * 64 + bh) * 4096 + idx];
        kvb[(size_t)bh * 4096 + idx] = f2bf(s * 0.125f);
    }
}

// ---------- W2t[b][e][h*64+i] = sum_j Wob[e][h*64+j] * kv[bh][i][j] ----------
__global__ __launch_bounds__(256, 2) void w2_gemm(
    const u16* __restrict__ Wob, const u16* __restrict__ kvb, u16* __restrict__ W2t) {
    __shared__ u16 Aw[256 * 64];
    __shared__ u16 Bw[64 * 64];
    const int eT = blockIdx.x, h = blockIdx.y, b = blockIdx.z;
    const int tid = threadIdx.x, w = tid >> 6, lane = tid & 63;
    const int srow = lane >> 3;
    const int scol = ((lane & 7) ^ srow) * 8;
#pragma unroll
    for (int j = 0; j < 8; ++j) {
        const int row = w * 64 + j * 8;
        async16(Wob + (size_t)(eT * 256 + row + srow) * 1024 + h * 64 + scol, &Aw[row * 64]);
    }
#pragma unroll
    for (int j = 0; j < 2; ++j) {
        const int row = w * 16 + j * 8;
        async16(kvb + ((size_t)(b * 16 + h) * 64 + row + srow) * 64 + scol, &Bw[row * 64]);
    }
    asm volatile("s_waitcnt vmcnt(0)" ::: "memory");
    __syncthreads();
    const int frow = lane & 15;
    const int xs0 = ((lane >> 4) ^ (frow & 7)) * 8;
    const int xs1 = ((4 + (lane >> 4)) ^ (frow & 7)) * 8;
    f32x4 acc[4][4] = {};
#pragma unroll
    for (int m = 0; m < 4; ++m) {
        bf16x8 a0 = *(const bf16x8*)&Aw[(w * 64 + m * 16 + frow) * 64 + xs0];
        bf16x8 a1 = *(const bf16x8*)&Aw[(w * 64 + m * 16 + frow) * 64 + xs1];
#pragma unroll
        for (int n = 0; n < 4; ++n) {
            bf16x8 b0 = *(const bf16x8*)&Bw[(n * 16 + frow) * 64 + xs0];
            bf16x8 b1 = *(const bf16x8*)&Bw[(n * 16 + frow) * 64 + xs1];
            acc[m][n] = __builtin_amdgcn_mfma_f32_16x16x32_bf16(a0, b0, acc[m][n], 0, 0, 0);
            acc[m][n] = __builtin_amdgcn_mfma_f32_16x16x32_bf16(a1, b1, acc[m][n], 0, 0, 0);
        }
    }
    const int rb4 = (lane >> 4) * 4, cx = lane & 15;
    u16* out = W2t + (size_t)b * 1048576;
#pragma unroll
    for (int m = 0; m < 4; ++m)
#pragma unroll
        for (int n = 0; n < 4; ++n)
#pragma unroll
            for (int r = 0; r < 4; ++r)
                out[(size_t)(eT * 256 + w * 64 + m * 16 + rb4 + r) * 1024 + h * 64 + n * 16 + cx] =
                    f2bf(acc[m][n][r]);
}

extern "C" void kernel_launch(void* const* d_in, const int* in_sizes, int n_in,
                              void* d_out, int out_size, void* d_ws, size_t ws_size,
                              hipStream_t stream) {
    const float* x  = (const float*)d_in[0];
    const float* Wq = (const float*)d_in[1];
    const float* Wk = (const float*)d_in[2];
    const float* Wv = (const float*)d_in[3];
    const float* Wo = (const float*)d_in[4];
    float* out = (float*)d_out;
    char* ws = (char*)d_ws;

    // workspace layout (bytes)
    u16*   xb    = (u16*)(ws);                    // [16384][1024] bf16   32 MB
    u16*   Kt    = (u16*)(ws + 33554432);         // [4][16][64][4096]    32 MB
    u16*   Vt    = (u16*)(ws + 67108864);         // [4][16][64][4096]    32 MB
    u16*   WkvT  = (u16*)(ws + 100663296);        // [2048][1024]  bf16    4 MB
    u16*   Wqb   = (u16*)(ws + 104857600);        // [1024][1024]  bf16    2 MB
    u16*   Wob   = (u16*)(ws + 106954752);        // [1024][1024]  bf16    2 MB
    float* Pkv   = (float*)(ws + 109051904);      // [8][64][64][64] f32   8 MB
    u16*   kvb   = (u16*)(ws + 117440512);        // [64][64][64] bf16   0.5 MB
    u16*   W2t   = (u16*)(ws + 117964800);        // [4][1024][1024] bf16  8 MB
    u16*   W3T   = (u16*)(ws + 126353408);        // [4][1024][1024] bf16  8 MB

    // one fused convert launch for x, Wq, Wo
    cvt3_f32_bf16<<<9216, 256, 0, stream>>>(x, xb, Wq, Wqb, Wo, Wob);
    transpose_cvt<<<dim3(32, 32, 2), dim3(32, 8), 0, stream>>>(Wk, Wv, WkvT);

    // [Kt|Vt] = xb @ [Wk|Wv], written transposed; grid 8*64=512 (%8==0)
    gemm8p<u16, true><<<512, 512, 0, stream>>>(xb, 1024, WkvT, 1024, (u16*)nullptr, 0,
                                               1024, 8, 0, Kt, Vt);

    kv_gemm<<<dim3(8, 64), 256, 0, stream>>>(Kt, Vt, Pkv);
    kv_reduce<<<64, 256, 0, stream>>>(Pkv, kvb);
    w2_gemm<<<dim3(4, 16, 4), 256, 0, stream>>>(Wob, kvb, W2t);

    // W3T[b*1024+e][d] = sum_k W2t[b][e][k] * Wq[d][k]  (M=4096, N=1024, K=1024)
    gemm128<<<dim3(8, 32), 256, 0, stream>>>(W2t, 1024, Wqb, 1024, W3T, 1024, 1024);

    // out = xb @ W3T^T (per-batch Bt); grid 4*64=256 (%8==0)
    gemm8p<float, false><<<256, 512, 0, stream>>>(xb, 1024, W3T, 1024, out, 1024, 1024, 4,
                                                  1048576, nullptr, nullptr);
}